// Round 3
// baseline (540.658 us; speedup 1.0000x reference)
//
#include <hip/hip_runtime.h>
#include <hip/hip_bf16.h>

// Problem constants (from reference)
#define NUM_AUTHOR 16604
#define EMB_D      300
#define BQ         32768      // batch of query nodes
#define NEDGE      1048576    // total edges
// Padded GEMM dims: K = 3*320 = 960 (each 300-dim section padded to 320), N = 320
#define KPAD 960
#define NPAD 320
#define DPAD 320              // padded embedding row (bf16 table)
#define NNODES 29059

// prep_all sub-grids
#define SEG_BLOCKS 4096                   // NEDGE/256
#define PW_BLOCKS  1200                   // NPAD*KPAD/256
#define CE_BLOCKS  4541                   // ceil(NNODES*40 uint4 / 256)

typedef __attribute__((ext_vector_type(8))) short bf16x8;   // 8 bf16 = 4 VGPRs
typedef __attribute__((ext_vector_type(4))) float f32x4;

__device__ __forceinline__ unsigned short f2bf(float f) {
  unsigned int u = __float_as_uint(f);
  u += 0x7fffu + ((u >> 16) & 1u);           // RNE
  return (unsigned short)(u >> 16);
}

// async global->LDS, 16B/lane. LDS dest is wave-uniform base + lane*16.
__device__ __forceinline__ void async_copy16(const void* g, void* lds_base) {
  __builtin_amdgcn_global_load_lds(
      (const __attribute__((address_space(1))) unsigned int*)g,
      (__attribute__((address_space(3))) unsigned int*)lds_base, 16, 0, 0);
}

// ---------------------------------------------------------------------------
// K1 (fused prep): seg_bounds + prep_w + conv_emb in one launch.
__global__ void prep_all(const int* __restrict__ seg, int* __restrict__ start,
                         const float* __restrict__ W1, unsigned short* __restrict__ Wt,
                         const float* __restrict__ emb, unsigned short* __restrict__ embB) {
  int blk = blockIdx.x;
  if (blk < SEG_BLOCKS) {
    // segment boundaries from sorted seg[]
    int i = blk * 256 + threadIdx.x;
    int s = seg[i];
    int prev = (i == 0) ? -1 : seg[i - 1];
    if (s != prev) {
      for (int b = prev + 1; b <= s; ++b) start[b] = i;
    }
    if (i == NEDGE - 1) {
      for (int b = s + 1; b <= BQ; ++b) start[b] = NEDGE;
    }
  } else if (blk < SEG_BLOCKS + PW_BLOCKS) {
    // pack fp32 W1 [300][900] -> bf16 Wt [NPAD][KPAD] (B^T, zero-padded)
    int i = (blk - SEG_BLOCKS) * 256 + threadIdx.x;
    int n = i / KPAD, k = i % KPAD;
    int sec = k / 320, kk = k % 320;
    unsigned short v = 0;
    if (n < 300 && kk < 300) v = f2bf(W1[n * 900 + sec * 300 + kk]);
    Wt[i] = v;
  } else {
    // convert fp32 emb [NNODES][300] -> bf16 embB [NNODES][320], uint4 units
    int i = (blk - SEG_BLOCKS - PW_BLOCKS) * 256 + threadIdx.x;  // uint4 index
    if (i >= NNODES * 40) return;
    int r = i / 40, q = i % 40;          // q: 8-elem granule within row
    const float* src = emb + (size_t)r * EMB_D + q * 8;
    unsigned int u[4] = {0, 0, 0, 0};
    if (q < 37) {                         // full 8 elems in-bounds (296 max)
      float4 v0 = *(const float4*)src;
      float4 v1 = *(const float4*)(src + 4);
      u[0] = (unsigned int)f2bf(v0.x) | ((unsigned int)f2bf(v0.y) << 16);
      u[1] = (unsigned int)f2bf(v0.z) | ((unsigned int)f2bf(v0.w) << 16);
      u[2] = (unsigned int)f2bf(v1.x) | ((unsigned int)f2bf(v1.y) << 16);
      u[3] = (unsigned int)f2bf(v1.z) | ((unsigned int)f2bf(v1.w) << 16);
    } else if (q == 37) {                 // elems 296..299 valid, rest pad
      float4 v0 = *(const float4*)src;
      u[0] = (unsigned int)f2bf(v0.x) | ((unsigned int)f2bf(v0.y) << 16);
      u[1] = (unsigned int)f2bf(v0.z) | ((unsigned int)f2bf(v0.w) << 16);
    }
    ((uint4*)embB)[i] = (uint4){u[0], u[1], u[2], u[3]};
  }
}

// ---------------------------------------------------------------------------
// branchless unpack-accumulate: atot += v; a1 += w*v  (w in {0,1}, uniform ->
// SGPR operand). Single basic block so gathers schedule above/around it.
__device__ __forceinline__ void accum8(uint4 p, float w,
                                       float2* atot, float2* a1) {
  unsigned int pk[4] = {p.x, p.y, p.z, p.w};
  #pragma unroll
  for (int k = 0; k < 4; ++k) {
    float lo = __uint_as_float(pk[k] << 16);
    float hi = __uint_as_float(pk[k] & 0xffff0000u);
    atot[k].x += lo;      atot[k].y += hi;
    a1[k].x   += w * lo;  a1[k].y   += w * hi;
  }
}

// ---------------------------------------------------------------------------
// K2 v3: per-segment mean pooling over bf16 table. One WAVE per query node
// (2 waves / 128-thread block). Scalarized index path (s_load + SALU type
// bits, gathers = saddr + 16*lane). ROLLING 8-slot gather buffer: per slot
// {consume p[q], reload p[q] from next group} -> 8 loads in flight at
// steady state with only 32 VGPRs of buffer (vs 64 for the round-2
// ping-pong, which rounded VGPR=88 up to the 128 granule and HALVED
// occupancy: 37.8%->19.5%, 89->105us). Budget ~56 VGPR; launch_bounds
// (128, 8) pins allocation at 64 -> 8 waves/SIMD. Tripwire: if WRITE_SIZE
// >> 61 MB next profile, the clamp spilled -> drop buffer depth instead.
__global__ __launch_bounds__(128, 8) void pool(
    const int* __restrict__ nodes, const int* __restrict__ neighbors,
    const int* __restrict__ start, const unsigned short* __restrict__ embB,
    unsigned short* __restrict__ comb) {
  int b = blockIdx.x * 2 + (threadIdx.x >> 6);
  int l = threadIdx.x & 63;
  if (l >= 40) return;                       // 40 lanes cover 320 bf16 = row
  int node = nodes[b];
  int qa = (node < NUM_AUTHOR) ? 1 : 0;

  // wave-uniform scalars (coerced so the compiler scalarizes the index path)
  int s0u  = __builtin_amdgcn_readfirstlane(start[b]);
  int remu = __builtin_amdgcn_readfirstlane(start[b + 1]) - s0u;
  int qau  = __builtin_amdgcn_readfirstlane(qa);
  const int* nb = neighbors + s0u;
  const unsigned short* col = embB + 8 * l;  // per-lane column base

  float2 atot[4], a1[4];
  #pragma unroll
  for (int k = 0; k < 4; ++k) {
    atot[k] = make_float2(0.f, 0.f);
    a1[k]   = make_float2(0.f, 0.f);
  }
  int c1 = 0;
  int ng = remu >> 3;          // full groups of 8 (avg degree 32 -> ~4)

  if (ng > 0) {
    uint4 p[8];
    float w[8];                // wave-uniform -> lives in SGPRs
    #pragma unroll
    for (int q = 0; q < 8; ++q) {          // prologue: fill all slots
      int ii = __builtin_amdgcn_readfirstlane(nb[q]);
      int bt = ((((ii < NUM_AUTHOR) ? 1 : 0) == qau) ? 1 : 0);
      c1 += bt;
      w[q] = bt ? 1.0f : 0.0f;
      p[q] = *(const uint4*)(col + (size_t)ii * DPAD);
    }
    for (int g = 1; g < ng; ++g) {         // steady state: consume+refill
      const int* gp = nb + g * 8;
      #pragma unroll
      for (int q = 0; q < 8; ++q) {
        accum8(p[q], w[q], atot, a1);
        int ii = __builtin_amdgcn_readfirstlane(gp[q]);
        int bt = ((((ii < NUM_AUTHOR) ? 1 : 0) == qau) ? 1 : 0);
        c1 += bt;
        w[q] = bt ? 1.0f : 0.0f;
        p[q] = *(const uint4*)(col + (size_t)ii * DPAD);
      }
    }
    #pragma unroll
    for (int q = 0; q < 8; ++q)            // drain
      accum8(p[q], w[q], atot, a1);
  }
  // tail edges (remu & 7)
  for (int j = ng * 8; j < remu; ++j) {
    int ii = __builtin_amdgcn_readfirstlane(nb[j]);
    int bt = ((((ii < NUM_AUTHOR) ? 1 : 0) == qau) ? 1 : 0);
    c1 += bt;
    float w = bt ? 1.0f : 0.0f;
    uint4 p = *(const uint4*)(col + (size_t)ii * DPAD);
    accum8(p, w, atot, a1);
  }

  int c2 = remu - c1;

  uint4 selfv = *(const uint4*)(col + (size_t)node * DPAD);
  float r1 = c1 ? 1.0f / (float)c1 : 0.0f;
  float r2 = c2 ? 1.0f / (float)c2 : 0.0f;
  unsigned int o1[4], o2[4];
  #pragma unroll
  for (int k = 0; k < 4; ++k) {
    float t1lo = c1 ? a1[k].x * r1 : 1.0f;
    float t1hi = c1 ? a1[k].y * r1 : 1.0f;
    float t2lo = c2 ? (atot[k].x - a1[k].x) * r2 : 1.0f;
    float t2hi = c2 ? (atot[k].y - a1[k].y) * r2 : 1.0f;
    o1[k] = (unsigned int)f2bf(t1lo) | ((unsigned int)f2bf(t1hi) << 16);
    o2[k] = (unsigned int)f2bf(t2lo) | ((unsigned int)f2bf(t2hi) << 16);
  }
  uint4* crow = (uint4*)(comb + (size_t)b * KPAD);   // 120 uint4 per row
  crow[l]      = selfv;                               // self section
  crow[40 + l] = (uint4){o1[0], o1[1], o1[2], o1[3]}; // t1 section
  crow[80 + l] = (uint4){o2[0], o2[1], o2[2], o2[3]}; // t2 section
}

// ---------------------------------------------------------------------------
// K3: GEMM  out[32768][300] = comb[32768][960](bf16) * Wt^T + b1, fp32 out.
// Block tile 128(M) x 160(N), BK=64, 256 threads / 4 waves, wave-tile 64x80:
// per ks: 9 ds_read_b128 feed 20 MFMA. 72 KB dynamic LDS -> 2 blocks/CU.
// Single-barrier dbuf K-loop. XOR swizzle (granule g ^= row&7, applied at
// the global fetch address) keeps ds_read conflict-free. Bijective
// XCD-chunked blockIdx swizzle (512 = 8*64) co-locates the bn=0/1 pair of
// each bm on one XCD so A rows are fetched once per XCD L2.
__global__ __launch_bounds__(256) void gemm(
    const unsigned short* __restrict__ A,    // comb [BQ][KPAD] bf16
    const unsigned short* __restrict__ Bt,   // Wt   [NPAD][KPAD] bf16
    const float* __restrict__ b1,
    float* __restrict__ out) {
  extern __shared__ unsigned short lds[];    // 73728 B
  unsigned short* As = lds;                  // [2][128*64]
  unsigned short* Bs = lds + 2 * 8192;       // [2][160*64]

  int tid  = threadIdx.x;
  int lane = tid & 63;
  int w    = tid >> 6;
  int quad = lane >> 4;
  int l16  = lane & 15;
  int P = blockIdx.x;                 // 0..511
  int L = (P & 7) * 64 + (P >> 3);    // XCD p%8 owns contiguous logical chunk
  int bm = L >> 1;                    // 256 row-tiles of 128
  int bn = L & 1;                     // 2 col-tiles of 160
  int wm = w >> 1, wn = w & 1;        // wave grid 2(M) x 2(N), tile 64x80

  f32x4 acc[4][5];
  #pragma unroll
  for (int i = 0; i < 4; ++i)
    #pragma unroll
    for (int j = 0; j < 5; ++j)
      acc[i][j] = (f32x4){0.f, 0.f, 0.f, 0.f};

  const size_t Abase = (size_t)bm * 128 * KPAD;
  const size_t Bbase = (size_t)bn * 160 * KPAD;

  auto stage = [&](int kt, int buf) {
    int k0 = kt * 64;
    char* Ad = (char*)(As + buf * 8192);
    char* Bd = (char*)(Bs + buf * 10240);
    // A: 16 chunks of 64 lanes x 16B. LDS slot (row, g) holds global granule
    // g ^ (row & 7) -> conflict-free ds_read later.
    for (int c = w; c < 16; c += 4) {
      int flat = c * 64 + lane;
      int row = flat >> 3, g = flat & 7;
      int kq = g ^ (row & 7);
      async_copy16(A + Abase + (size_t)row * KPAD + k0 + kq * 8, Ad + c * 1024);
    }
    // B^T: 20 chunks
    for (int c = w; c < 20; c += 4) {
      int flat = c * 64 + lane;
      int row = flat >> 3, g = flat & 7;
      int kq = g ^ (row & 7);
      async_copy16(Bt + Bbase + (size_t)row * KPAD + k0 + kq * 8, Bd + c * 1024);
    }
  };

  stage(0, 0);
  for (int kt = 0; kt < KPAD / 64; ++kt) {
    int cur = kt & 1;
    __syncthreads();                    // drains stage(kt); syncs buffers
    if (kt + 1 < KPAD / 64) stage(kt + 1, cur ^ 1);
    const unsigned short* Ac = As + cur * 8192;
    const unsigned short* Bc = Bs + cur * 10240;
    #pragma unroll
    for (int ks = 0; ks < 2; ++ks) {
      int gi = ks * 4 + quad;           // k-granule index within BK=64
      bf16x8 af[4], bfr[5];
      #pragma unroll
      for (int rt = 0; rt < 4; ++rt) {
        int row = wm * 64 + rt * 16 + l16;
        af[rt] = *(const bf16x8*)&Ac[row * 64 + ((gi ^ (row & 7)) << 3)];
      }
      #pragma unroll
      for (int ct = 0; ct < 5; ++ct) {
        int row = wn * 80 + ct * 16 + l16;
        bfr[ct] = *(const bf16x8*)&Bc[row * 64 + ((gi ^ (row & 7)) << 3)];
      }
      #pragma unroll
      for (int rt = 0; rt < 4; ++rt)
        #pragma unroll
        for (int ct = 0; ct < 5; ++ct)
          acc[rt][ct] = __builtin_amdgcn_mfma_f32_16x16x32_bf16(
              af[rt], bfr[ct], acc[rt][ct], 0, 0, 0);
    }
  }

  // Epilogue: C[m][n], m = m0+rt*16+quad*4+r, n = n0+ct*16+l16
  int m0 = bm * 128 + wm * 64;
  int n0 = bn * 160 + wn * 80;
  for (int ct = 0; ct < 5; ++ct) {
    int n = n0 + ct * 16 + l16;
    if (n >= 300) continue;
    float bias = b1[n];
    for (int rt = 0; rt < 4; ++rt) {
      int m = m0 + rt * 16 + quad * 4;
      for (int r = 0; r < 4; ++r)
        out[(size_t)(m + r) * 300 + n] = acc[rt][ct][r] + bias;
    }
  }
}

// ---------------------------------------------------------------------------
// Fallback GEMM (if >64KB dynamic-LDS opt-in fails): 64x160 static-LDS tile.
__global__ __launch_bounds__(256) void gemm_fb(
    const unsigned short* __restrict__ A,    // comb [BQ][KPAD] bf16
    const unsigned short* __restrict__ Bt,   // Wt   [NPAD][KPAD] bf16
    const float* __restrict__ b1,
    float* __restrict__ out) {
  __shared__ __align__(16) unsigned short As[2][64 * 64];   // 8 KB each
  __shared__ __align__(16) unsigned short Bs[2][160 * 64];  // 20 KB each

  int tid  = threadIdx.x;
  int lane = tid & 63;
  int w    = tid >> 6;
  int quad = lane >> 4;
  int l16  = lane & 15;
  int bm = blockIdx.x >> 1;     // 512 row-tiles of 64
  int bn = blockIdx.x & 1;      // 2 col-tiles of 160
  int wm = w >> 1, wn = w & 1;

  f32x4 acc[2][5];
  for (int i = 0; i < 2; ++i)
    for (int j = 0; j < 5; ++j)
      acc[i][j] = (f32x4){0.f, 0.f, 0.f, 0.f};

  const size_t Abase = (size_t)bm * 64 * KPAD;
  const size_t Bbase = (size_t)bn * 160 * KPAD;

  auto stage = [&](int kt, int buf) {
    int k0 = kt * 64;
    for (int c = w; c < 8; c += 4) {
      int flat = c * 64 + lane;
      int row = flat >> 3, g = flat & 7;
      int kq = g ^ (row & 7);
      const unsigned short* gp = A + Abase + (size_t)row * KPAD + k0 + kq * 8;
      async_copy16(gp, (char*)&As[buf][0] + c * 1024);
    }
    for (int c = w; c < 20; c += 4) {
      int flat = c * 64 + lane;
      int row = flat >> 3, g = flat & 7;
      int kq = g ^ (row & 7);
      const unsigned short* gp = Bt + Bbase + (size_t)row * KPAD + k0 + kq * 8;
      async_copy16(gp, (char*)&Bs[buf][0] + c * 1024);
    }
  };

  stage(0, 0);
  for (int kt = 0; kt < KPAD / 64; ++kt) {
    int cur = kt & 1;
    __syncthreads();
    if (kt + 1 < KPAD / 64) stage(kt + 1, cur ^ 1);
    #pragma unroll
    for (int ks = 0; ks < 2; ++ks) {
      int gi = ks * 4 + quad;
      bf16x8 af[2], bfr[5];
      #pragma unroll
      for (int rt = 0; rt < 2; ++rt) {
        int row = wm * 32 + rt * 16 + l16;
        af[rt] = *(const bf16x8*)&As[cur][row * 64 + ((gi ^ (row & 7)) << 3)];
      }
      #pragma unroll
      for (int ct = 0; ct < 5; ++ct) {
        int row = wn * 80 + ct * 16 + l16;
        bfr[ct] = *(const bf16x8*)&Bs[cur][row * 64 + ((gi ^ (row & 7)) << 3)];
      }
      #pragma unroll
      for (int rt = 0; rt < 2; ++rt)
        #pragma unroll
        for (int ct = 0; ct < 5; ++ct)
          acc[rt][ct] = __builtin_amdgcn_mfma_f32_16x16x32_bf16(
              af[rt], bfr[ct], acc[rt][ct], 0, 0, 0);
    }
  }

  int m0 = bm * 64 + wm * 32;
  int n0 = bn * 160 + wn * 80;
  for (int ct = 0; ct < 5; ++ct) {
    int n = n0 + ct * 16 + l16;
    if (n >= 300) continue;
    float bias = b1[n];
    for (int rt = 0; rt < 2; ++rt) {
      int m = m0 + rt * 16 + quad * 4;
      for (int r = 0; r < 4; ++r)
        out[(size_t)(m + r) * 300 + n] = acc[rt][ct][r] + bias;
    }
  }
}

// ---------------------------------------------------------------------------
// Fallback pool (ws too small for bf16 table): fp32 pool.
__global__ __launch_bounds__(128) void pool_f32(
    const int* __restrict__ nodes, const int* __restrict__ neighbors,
    const int* __restrict__ start, const float* __restrict__ emb,
    unsigned short* __restrict__ comb) {
  int b = blockIdx.x;
  int t = threadIdx.x;
  if (t >= 80) return;
  int s0 = start[b], s1 = start[b + 1];
  int node = nodes[b];
  int qa = (node < NUM_AUTHOR) ? 1 : 0;
  bool act = (t < 75);
  float a1x = 0.f, a1y = 0.f, a1z = 0.f, a1w = 0.f;
  float a2x = 0.f, a2y = 0.f, a2z = 0.f, a2w = 0.f;
  int c1 = 0;
  #pragma unroll 2
  for (int j = s0; j < s1; ++j) {
    int nb = neighbors[j];
    int fl = (((nb < NUM_AUTHOR) ? 1 : 0) == qa) ? 1 : 0;
    c1 += fl;
    if (act) {
      const float4 v = *(const float4*)(emb + (size_t)nb * EMB_D + 4 * t);
      float w = fl ? 1.0f : 0.0f;
      float u = 1.0f - w;
      a1x += w * v.x; a1y += w * v.y; a1z += w * v.z; a1w += w * v.w;
      a2x += u * v.x; a2y += u * v.y; a2z += u * v.z; a2w += u * v.w;
    }
  }
  int c2 = (s1 - s0) - c1;
  unsigned int ps0 = 0, ps1 = 0, p10 = 0, p11 = 0, p20 = 0, p21 = 0;
  if (act) {
    const float4 sv = *(const float4*)(emb + (size_t)node * EMB_D + 4 * t);
    float r1 = c1 ? 1.0f / (float)c1 : 0.0f;
    float r2 = c2 ? 1.0f / (float)c2 : 0.0f;
    float t1x = c1 ? a1x * r1 : 1.0f, t1y = c1 ? a1y * r1 : 1.0f;
    float t1z = c1 ? a1z * r1 : 1.0f, t1w = c1 ? a1w * r1 : 1.0f;
    float t2x = c2 ? a2x * r2 : 1.0f, t2y = c2 ? a2y * r2 : 1.0f;
    float t2z = c2 ? a2z * r2 : 1.0f, t2w = c2 ? a2w * r2 : 1.0f;
    ps0 = (unsigned int)f2bf(sv.x) | ((unsigned int)f2bf(sv.y) << 16);
    ps1 = (unsigned int)f2bf(sv.z) | ((unsigned int)f2bf(sv.w) << 16);
    p10 = (unsigned int)f2bf(t1x) | ((unsigned int)f2bf(t1y) << 16);
    p11 = (unsigned int)f2bf(t1z) | ((unsigned int)f2bf(t1w) << 16);
    p20 = (unsigned int)f2bf(t2x) | ((unsigned int)f2bf(t2y) << 16);
    p21 = (unsigned int)f2bf(t2z) | ((unsigned int)f2bf(t2w) << 16);
  }
  unsigned int* crow = (unsigned int*)(comb + (size_t)b * KPAD);
  crow[2 * t]       = ps0;  crow[2 * t + 1]       = ps1;
  crow[160 + 2 * t] = p10;  crow[160 + 2 * t + 1] = p11;
  crow[320 + 2 * t] = p20;  crow[320 + 2 * t + 1] = p21;
}

__global__ void seg_bounds_only(const int* __restrict__ seg, int* __restrict__ start) {
  int i = blockIdx.x * 256 + threadIdx.x;
  if (i >= NEDGE) return;
  int s = seg[i];
  int prev = (i == 0) ? -1 : seg[i - 1];
  if (s != prev) for (int b = prev + 1; b <= s; ++b) start[b] = i;
  if (i == NEDGE - 1) for (int b = s + 1; b <= BQ; ++b) start[b] = NEDGE;
}
__global__ void prep_w_only(const float* __restrict__ W1, unsigned short* __restrict__ Wt) {
  int i = blockIdx.x * 256 + threadIdx.x;
  if (i >= NPAD * KPAD) return;
  int n = i / KPAD, k = i % KPAD;
  int sec = k / 320, kk = k % 320;
  unsigned short v = 0;
  if (n < 300 && kk < 300) v = f2bf(W1[n * 900 + sec * 300 + kk]);
  Wt[i] = v;
}

// ---------------------------------------------------------------------------
extern "C" void kernel_launch(void* const* d_in, const int* in_sizes, int n_in,
                              void* d_out, int out_size, void* d_ws, size_t ws_size,
                              hipStream_t stream) {
  const int* nodes     = (const int*)d_in[0];
  const int* seg       = (const int*)d_in[1];
  const int* neighbors = (const int*)d_in[2];
  const float* emb     = (const float*)d_in[3];
  const float* W1      = (const float*)d_in[4];
  const float* b1      = (const float*)d_in[5];
  float* out           = (float*)d_out;

  // Workspace layout:
  //   [0, 131584)       start[BQ+1] int
  //   [131584, 746496)  Wt [320][960] bf16 (614400 B + pad)
  //   [746496, 63661056)            comb [32768][960] bf16
  //   [63661056, 82258816)          embB [29059][320] bf16
  char* ws = (char*)d_ws;
  int* start           = (int*)ws;
  unsigned short* Wt   = (unsigned short*)(ws + 131584);
  unsigned short* comb = (unsigned short*)(ws + 746496);
  unsigned short* embB = (unsigned short*)(ws + 63661056);
  const size_t WS_NEEDED = 82258816;

  // one-time opt-in for 72 KB dynamic LDS on the big-tile GEMM
  static int big_lds_ok = -1;
  if (big_lds_ok < 0) {
    big_lds_ok = (hipFuncSetAttribute(
                      reinterpret_cast<const void*>(gemm),
                      hipFuncAttributeMaxDynamicSharedMemorySize,
                      73728) == hipSuccess) ? 1 : 0;
  }

  if (ws_size >= WS_NEEDED) {
    prep_all<<<SEG_BLOCKS + PW_BLOCKS + CE_BLOCKS, 256, 0, stream>>>(
        seg, start, W1, Wt, emb, embB);
    pool<<<BQ / 2, 128, 0, stream>>>(nodes, neighbors, start, embB, comb);
  } else {
    seg_bounds_only<<<SEG_BLOCKS, 256, 0, stream>>>(seg, start);
    prep_w_only<<<PW_BLOCKS, 256, 0, stream>>>(W1, Wt);
    pool_f32<<<BQ, 128, 0, stream>>>(nodes, neighbors, start, emb, comb);
  }
  if (big_lds_ok) {
    gemm<<<512, 256, 73728, stream>>>(comb, Wt, b1, out);
  } else {
    gemm_fb<<<1024, 256, 0, stream>>>(comb, Wt, b1, out);
  }
}

// Round 4
// 212.714 us; speedup vs baseline: 2.5417x; 2.5417x over previous
//
#include <hip/hip_runtime.h>
#include <hip/hip_bf16.h>

// Problem constants (from reference)
#define NUM_AUTHOR 16604
#define EMB_D      300
#define BQ         32768      // batch of query nodes
#define NEDGE      1048576    // total edges
// Padded GEMM dims: K = 3*320 = 960 (each 300-dim section padded to 320), N = 320
#define KPAD 960
#define NPAD 320
#define DPAD 320              // padded embedding row (bf16 table)
#define NNODES 29059

// prep_all sub-grids
#define SEG_BLOCKS 4096                   // NEDGE/256
#define PW_BLOCKS  1200                   // NPAD*KPAD/256
#define CE_BLOCKS  4541                   // ceil(NNODES*40 uint4 / 256)

typedef __attribute__((ext_vector_type(8))) short bf16x8;   // 8 bf16 = 4 VGPRs
typedef __attribute__((ext_vector_type(4))) float f32x4;

__device__ __forceinline__ unsigned short f2bf(float f) {
  unsigned int u = __float_as_uint(f);
  u += 0x7fffu + ((u >> 16) & 1u);           // RNE
  return (unsigned short)(u >> 16);
}

// async global->LDS, 16B/lane. LDS dest is wave-uniform base + lane*16.
__device__ __forceinline__ void async_copy16(const void* g, void* lds_base) {
  __builtin_amdgcn_global_load_lds(
      (const __attribute__((address_space(1))) unsigned int*)g,
      (__attribute__((address_space(3))) unsigned int*)lds_base, 16, 0, 0);
}

// ---------------------------------------------------------------------------
// K1 (fused prep): seg_bounds + prep_w + conv_emb in one launch.
__global__ void prep_all(const int* __restrict__ seg, int* __restrict__ start,
                         const float* __restrict__ W1, unsigned short* __restrict__ Wt,
                         const float* __restrict__ emb, unsigned short* __restrict__ embB) {
  int blk = blockIdx.x;
  if (blk < SEG_BLOCKS) {
    // segment boundaries from sorted seg[]
    int i = blk * 256 + threadIdx.x;
    int s = seg[i];
    int prev = (i == 0) ? -1 : seg[i - 1];
    if (s != prev) {
      for (int b = prev + 1; b <= s; ++b) start[b] = i;
    }
    if (i == NEDGE - 1) {
      for (int b = s + 1; b <= BQ; ++b) start[b] = NEDGE;
    }
  } else if (blk < SEG_BLOCKS + PW_BLOCKS) {
    // pack fp32 W1 [300][900] -> bf16 Wt [NPAD][KPAD] (B^T, zero-padded)
    int i = (blk - SEG_BLOCKS) * 256 + threadIdx.x;
    int n = i / KPAD, k = i % KPAD;
    int sec = k / 320, kk = k % 320;
    unsigned short v = 0;
    if (n < 300 && kk < 300) v = f2bf(W1[n * 900 + sec * 300 + kk]);
    Wt[i] = v;
  } else {
    // convert fp32 emb [NNODES][300] -> bf16 embB [NNODES][320], uint4 units
    int i = (blk - SEG_BLOCKS - PW_BLOCKS) * 256 + threadIdx.x;  // uint4 index
    if (i >= NNODES * 40) return;
    int r = i / 40, q = i % 40;          // q: 8-elem granule within row
    const float* src = emb + (size_t)r * EMB_D + q * 8;
    unsigned int u[4] = {0, 0, 0, 0};
    if (q < 37) {                         // full 8 elems in-bounds (296 max)
      float4 v0 = *(const float4*)src;
      float4 v1 = *(const float4*)(src + 4);
      u[0] = (unsigned int)f2bf(v0.x) | ((unsigned int)f2bf(v0.y) << 16);
      u[1] = (unsigned int)f2bf(v0.z) | ((unsigned int)f2bf(v0.w) << 16);
      u[2] = (unsigned int)f2bf(v1.x) | ((unsigned int)f2bf(v1.y) << 16);
      u[3] = (unsigned int)f2bf(v1.z) | ((unsigned int)f2bf(v1.w) << 16);
    } else if (q == 37) {                 // elems 296..299 valid, rest pad
      float4 v0 = *(const float4*)src;
      u[0] = (unsigned int)f2bf(v0.x) | ((unsigned int)f2bf(v0.y) << 16);
      u[1] = (unsigned int)f2bf(v0.z) | ((unsigned int)f2bf(v0.w) << 16);
    }
    ((uint4*)embB)[i] = (uint4){u[0], u[1], u[2], u[3]};
  }
}

// ---------------------------------------------------------------------------
// branchless unpack-accumulate: atot += v; a1 += w*v  (w in {0,1}, uniform ->
// SGPR operand). Single basic block so gathers schedule above/around it.
__device__ __forceinline__ void accum8(uint4 p, float w,
                                       float2* atot, float2* a1) {
  unsigned int pk[4] = {p.x, p.y, p.z, p.w};
  #pragma unroll
  for (int k = 0; k < 4; ++k) {
    float lo = __uint_as_float(pk[k] << 16);
    float hi = __uint_as_float(pk[k] & 0xffff0000u);
    atot[k].x += lo;      atot[k].y += hi;
    a1[k].x   += w * lo;  a1[k].y   += w * hi;
  }
}

// ---------------------------------------------------------------------------
// K2 v4: per-segment mean pooling over bf16 table. One WAVE per query node
// (2 waves / 128-thread block). Scalarized index path (s_load + SALU type
// bits, gathers = saddr + 16*lane). ROLLING 8-slot gather buffer: per slot
// {consume p[q], reload p[q] from next group} -> 8 loads in flight with only
// 32 VGPRs of buffer. Register ledger: 32 buf + 16 acc + ~8 misc = ~56.
// NO min-waves launch-bound arg: this toolchain maps (128,4)->64-reg clamp
// and (128,8)->32-reg clamp (round-3: VGPR=32, 1.4 GB scratch, 415us).
// Natural allocation <=64 -> 8 waves/SIMD without spill.
__global__ __launch_bounds__(128) void pool(
    const int* __restrict__ nodes, const int* __restrict__ neighbors,
    const int* __restrict__ start, const unsigned short* __restrict__ embB,
    unsigned short* __restrict__ comb) {
  int b = blockIdx.x * 2 + (threadIdx.x >> 6);
  int l = threadIdx.x & 63;
  if (l >= 40) return;                       // 40 lanes cover 320 bf16 = row
  int node = nodes[b];
  int qa = (node < NUM_AUTHOR) ? 1 : 0;

  // wave-uniform scalars (coerced so the compiler scalarizes the index path)
  int s0u  = __builtin_amdgcn_readfirstlane(start[b]);
  int remu = __builtin_amdgcn_readfirstlane(start[b + 1]) - s0u;
  int qau  = __builtin_amdgcn_readfirstlane(qa);
  const int* nb = neighbors + s0u;
  const unsigned short* col = embB + 8 * l;  // per-lane column base

  float2 atot[4], a1[4];
  #pragma unroll
  for (int k = 0; k < 4; ++k) {
    atot[k] = make_float2(0.f, 0.f);
    a1[k]   = make_float2(0.f, 0.f);
  }
  int c1 = 0;
  int ng = remu >> 3;          // full groups of 8 (avg degree 32 -> ~4)

  if (ng > 0) {
    uint4 p[8];
    float w[8];                // wave-uniform -> lives in SGPRs
    #pragma unroll
    for (int q = 0; q < 8; ++q) {          // prologue: fill all slots
      int ii = __builtin_amdgcn_readfirstlane(nb[q]);
      int bt = ((((ii < NUM_AUTHOR) ? 1 : 0) == qau) ? 1 : 0);
      c1 += bt;
      w[q] = bt ? 1.0f : 0.0f;
      p[q] = *(const uint4*)(col + (size_t)ii * DPAD);
    }
    for (int g = 1; g < ng; ++g) {         // steady state: consume+refill
      const int* gp = nb + g * 8;
      #pragma unroll
      for (int q = 0; q < 8; ++q) {
        accum8(p[q], w[q], atot, a1);
        int ii = __builtin_amdgcn_readfirstlane(gp[q]);
        int bt = ((((ii < NUM_AUTHOR) ? 1 : 0) == qau) ? 1 : 0);
        c1 += bt;
        w[q] = bt ? 1.0f : 0.0f;
        p[q] = *(const uint4*)(col + (size_t)ii * DPAD);
      }
    }
    #pragma unroll
    for (int q = 0; q < 8; ++q)            // drain
      accum8(p[q], w[q], atot, a1);
  }
  // tail edges (remu & 7)
  for (int j = ng * 8; j < remu; ++j) {
    int ii = __builtin_amdgcn_readfirstlane(nb[j]);
    int bt = ((((ii < NUM_AUTHOR) ? 1 : 0) == qau) ? 1 : 0);
    c1 += bt;
    float w = bt ? 1.0f : 0.0f;
    uint4 p = *(const uint4*)(col + (size_t)ii * DPAD);
    accum8(p, w, atot, a1);
  }

  int c2 = remu - c1;

  uint4 selfv = *(const uint4*)(col + (size_t)node * DPAD);
  float r1 = c1 ? 1.0f / (float)c1 : 0.0f;
  float r2 = c2 ? 1.0f / (float)c2 : 0.0f;
  unsigned int o1[4], o2[4];
  #pragma unroll
  for (int k = 0; k < 4; ++k) {
    float t1lo = c1 ? a1[k].x * r1 : 1.0f;
    float t1hi = c1 ? a1[k].y * r1 : 1.0f;
    float t2lo = c2 ? (atot[k].x - a1[k].x) * r2 : 1.0f;
    float t2hi = c2 ? (atot[k].y - a1[k].y) * r2 : 1.0f;
    o1[k] = (unsigned int)f2bf(t1lo) | ((unsigned int)f2bf(t1hi) << 16);
    o2[k] = (unsigned int)f2bf(t2lo) | ((unsigned int)f2bf(t2hi) << 16);
  }
  uint4* crow = (uint4*)(comb + (size_t)b * KPAD);   // 120 uint4 per row
  crow[l]      = selfv;                               // self section
  crow[40 + l] = (uint4){o1[0], o1[1], o1[2], o1[3]}; // t1 section
  crow[80 + l] = (uint4){o2[0], o2[1], o2[2], o2[3]}; // t2 section
}

// ---------------------------------------------------------------------------
// K3: GEMM  out[32768][300] = comb[32768][960](bf16) * Wt^T + b1, fp32 out.
// Block tile 128(M) x 160(N), BK=64, 256 threads / 4 waves, wave-tile 64x80:
// per ks: 9 ds_read_b128 feed 20 MFMA. 72 KB dynamic LDS -> 2 blocks/CU.
// Single-barrier dbuf K-loop. XOR swizzle (granule g ^= row&7, applied at
// the global fetch address) keeps ds_read conflict-free. Bijective
// XCD-chunked blockIdx swizzle (512 = 8*64) co-locates the bn=0/1 pair of
// each bm on one XCD so A rows are fetched once per XCD L2.
__global__ __launch_bounds__(256) void gemm(
    const unsigned short* __restrict__ A,    // comb [BQ][KPAD] bf16
    const unsigned short* __restrict__ Bt,   // Wt   [NPAD][KPAD] bf16
    const float* __restrict__ b1,
    float* __restrict__ out) {
  extern __shared__ unsigned short lds[];    // 73728 B
  unsigned short* As = lds;                  // [2][128*64]
  unsigned short* Bs = lds + 2 * 8192;       // [2][160*64]

  int tid  = threadIdx.x;
  int lane = tid & 63;
  int w    = tid >> 6;
  int quad = lane >> 4;
  int l16  = lane & 15;
  int P = blockIdx.x;                 // 0..511
  int L = (P & 7) * 64 + (P >> 3);    // XCD p%8 owns contiguous logical chunk
  int bm = L >> 1;                    // 256 row-tiles of 128
  int bn = L & 1;                     // 2 col-tiles of 160
  int wm = w >> 1, wn = w & 1;        // wave grid 2(M) x 2(N), tile 64x80

  f32x4 acc[4][5];
  #pragma unroll
  for (int i = 0; i < 4; ++i)
    #pragma unroll
    for (int j = 0; j < 5; ++j)
      acc[i][j] = (f32x4){0.f, 0.f, 0.f, 0.f};

  const size_t Abase = (size_t)bm * 128 * KPAD;
  const size_t Bbase = (size_t)bn * 160 * KPAD;

  auto stage = [&](int kt, int buf) {
    int k0 = kt * 64;
    char* Ad = (char*)(As + buf * 8192);
    char* Bd = (char*)(Bs + buf * 10240);
    // A: 16 chunks of 64 lanes x 16B. LDS slot (row, g) holds global granule
    // g ^ (row & 7) -> conflict-free ds_read later.
    for (int c = w; c < 16; c += 4) {
      int flat = c * 64 + lane;
      int row = flat >> 3, g = flat & 7;
      int kq = g ^ (row & 7);
      async_copy16(A + Abase + (size_t)row * KPAD + k0 + kq * 8, Ad + c * 1024);
    }
    // B^T: 20 chunks
    for (int c = w; c < 20; c += 4) {
      int flat = c * 64 + lane;
      int row = flat >> 3, g = flat & 7;
      int kq = g ^ (row & 7);
      async_copy16(Bt + Bbase + (size_t)row * KPAD + k0 + kq * 8, Bd + c * 1024);
    }
  };

  stage(0, 0);
  for (int kt = 0; kt < KPAD / 64; ++kt) {
    int cur = kt & 1;
    __syncthreads();                    // drains stage(kt); syncs buffers
    if (kt + 1 < KPAD / 64) stage(kt + 1, cur ^ 1);
    const unsigned short* Ac = As + cur * 8192;
    const unsigned short* Bc = Bs + cur * 10240;
    #pragma unroll
    for (int ks = 0; ks < 2; ++ks) {
      int gi = ks * 4 + quad;           // k-granule index within BK=64
      bf16x8 af[4], bfr[5];
      #pragma unroll
      for (int rt = 0; rt < 4; ++rt) {
        int row = wm * 64 + rt * 16 + l16;
        af[rt] = *(const bf16x8*)&Ac[row * 64 + ((gi ^ (row & 7)) << 3)];
      }
      #pragma unroll
      for (int ct = 0; ct < 5; ++ct) {
        int row = wn * 80 + ct * 16 + l16;
        bfr[ct] = *(const bf16x8*)&Bc[row * 64 + ((gi ^ (row & 7)) << 3)];
      }
      #pragma unroll
      for (int rt = 0; rt < 4; ++rt)
        #pragma unroll
        for (int ct = 0; ct < 5; ++ct)
          acc[rt][ct] = __builtin_amdgcn_mfma_f32_16x16x32_bf16(
              af[rt], bfr[ct], acc[rt][ct], 0, 0, 0);
    }
  }

  // Epilogue: C[m][n], m = m0+rt*16+quad*4+r, n = n0+ct*16+l16
  int m0 = bm * 128 + wm * 64;
  int n0 = bn * 160 + wn * 80;
  for (int ct = 0; ct < 5; ++ct) {
    int n = n0 + ct * 16 + l16;
    if (n >= 300) continue;
    float bias = b1[n];
    for (int rt = 0; rt < 4; ++rt) {
      int m = m0 + rt * 16 + quad * 4;
      for (int r = 0; r < 4; ++r)
        out[(size_t)(m + r) * 300 + n] = acc[rt][ct][r] + bias;
    }
  }
}

// ---------------------------------------------------------------------------
// Fallback GEMM (if >64KB dynamic-LDS opt-in fails): 64x160 static-LDS tile.
__global__ __launch_bounds__(256) void gemm_fb(
    const unsigned short* __restrict__ A,    // comb [BQ][KPAD] bf16
    const unsigned short* __restrict__ Bt,   // Wt   [NPAD][KPAD] bf16
    const float* __restrict__ b1,
    float* __restrict__ out) {
  __shared__ __align__(16) unsigned short As[2][64 * 64];   // 8 KB each
  __shared__ __align__(16) unsigned short Bs[2][160 * 64];  // 20 KB each

  int tid  = threadIdx.x;
  int lane = tid & 63;
  int w    = tid >> 6;
  int quad = lane >> 4;
  int l16  = lane & 15;
  int bm = blockIdx.x >> 1;     // 512 row-tiles of 64
  int bn = blockIdx.x & 1;      // 2 col-tiles of 160
  int wm = w >> 1, wn = w & 1;

  f32x4 acc[2][5];
  for (int i = 0; i < 2; ++i)
    for (int j = 0; j < 5; ++j)
      acc[i][j] = (f32x4){0.f, 0.f, 0.f, 0.f};

  const size_t Abase = (size_t)bm * 64 * KPAD;
  const size_t Bbase = (size_t)bn * 160 * KPAD;

  auto stage = [&](int kt, int buf) {
    int k0 = kt * 64;
    for (int c = w; c < 8; c += 4) {
      int flat = c * 64 + lane;
      int row = flat >> 3, g = flat & 7;
      int kq = g ^ (row & 7);
      const unsigned short* gp = A + Abase + (size_t)row * KPAD + k0 + kq * 8;
      async_copy16(gp, (char*)&As[buf][0] + c * 1024);
    }
    for (int c = w; c < 20; c += 4) {
      int flat = c * 64 + lane;
      int row = flat >> 3, g = flat & 7;
      int kq = g ^ (row & 7);
      const unsigned short* gp = Bt + Bbase + (size_t)row * KPAD + k0 + kq * 8;
      async_copy16(gp, (char*)&Bs[buf][0] + c * 1024);
    }
  };

  stage(0, 0);
  for (int kt = 0; kt < KPAD / 64; ++kt) {
    int cur = kt & 1;
    __syncthreads();
    if (kt + 1 < KPAD / 64) stage(kt + 1, cur ^ 1);
    #pragma unroll
    for (int ks = 0; ks < 2; ++ks) {
      int gi = ks * 4 + quad;
      bf16x8 af[2], bfr[5];
      #pragma unroll
      for (int rt = 0; rt < 2; ++rt) {
        int row = wm * 32 + rt * 16 + l16;
        af[rt] = *(const bf16x8*)&As[cur][row * 64 + ((gi ^ (row & 7)) << 3)];
      }
      #pragma unroll
      for (int ct = 0; ct < 5; ++ct) {
        int row = wn * 80 + ct * 16 + l16;
        bfr[ct] = *(const bf16x8*)&Bs[cur][row * 64 + ((gi ^ (row & 7)) << 3)];
      }
      #pragma unroll
      for (int rt = 0; rt < 2; ++rt)
        #pragma unroll
        for (int ct = 0; ct < 5; ++ct)
          acc[rt][ct] = __builtin_amdgcn_mfma_f32_16x16x32_bf16(
              af[rt], bfr[ct], acc[rt][ct], 0, 0, 0);
    }
  }

  int m0 = bm * 64 + wm * 32;
  int n0 = bn * 160 + wn * 80;
  for (int ct = 0; ct < 5; ++ct) {
    int n = n0 + ct * 16 + l16;
    if (n >= 300) continue;
    float bias = b1[n];
    for (int rt = 0; rt < 2; ++rt) {
      int m = m0 + rt * 16 + quad * 4;
      for (int r = 0; r < 4; ++r)
        out[(size_t)(m + r) * 300 + n] = acc[rt][ct][r] + bias;
    }
  }
}

// ---------------------------------------------------------------------------
// Fallback pool (ws too small for bf16 table): fp32 pool.
__global__ __launch_bounds__(128) void pool_f32(
    const int* __restrict__ nodes, const int* __restrict__ neighbors,
    const int* __restrict__ start, const float* __restrict__ emb,
    unsigned short* __restrict__ comb) {
  int b = blockIdx.x;
  int t = threadIdx.x;
  if (t >= 80) return;
  int s0 = start[b], s1 = start[b + 1];
  int node = nodes[b];
  int qa = (node < NUM_AUTHOR) ? 1 : 0;
  bool act = (t < 75);
  float a1x = 0.f, a1y = 0.f, a1z = 0.f, a1w = 0.f;
  float a2x = 0.f, a2y = 0.f, a2z = 0.f, a2w = 0.f;
  int c1 = 0;
  #pragma unroll 2
  for (int j = s0; j < s1; ++j) {
    int nb = neighbors[j];
    int fl = (((nb < NUM_AUTHOR) ? 1 : 0) == qa) ? 1 : 0;
    c1 += fl;
    if (act) {
      const float4 v = *(const float4*)(emb + (size_t)nb * EMB_D + 4 * t);
      float w = fl ? 1.0f : 0.0f;
      float u = 1.0f - w;
      a1x += w * v.x; a1y += w * v.y; a1z += w * v.z; a1w += w * v.w;
      a2x += u * v.x; a2y += u * v.y; a2z += u * v.z; a2w += u * v.w;
    }
  }
  int c2 = (s1 - s0) - c1;
  unsigned int ps0 = 0, ps1 = 0, p10 = 0, p11 = 0, p20 = 0, p21 = 0;
  if (act) {
    const float4 sv = *(const float4*)(emb + (size_t)node * EMB_D + 4 * t);
    float r1 = c1 ? 1.0f / (float)c1 : 0.0f;
    float r2 = c2 ? 1.0f / (float)c2 : 0.0f;
    float t1x = c1 ? a1x * r1 : 1.0f, t1y = c1 ? a1y * r1 : 1.0f;
    float t1z = c1 ? a1z * r1 : 1.0f, t1w = c1 ? a1w * r1 : 1.0f;
    float t2x = c2 ? a2x * r2 : 1.0f, t2y = c2 ? a2y * r2 : 1.0f;
    float t2z = c2 ? a2z * r2 : 1.0f, t2w = c2 ? a2w * r2 : 1.0f;
    ps0 = (unsigned int)f2bf(sv.x) | ((unsigned int)f2bf(sv.y) << 16);
    ps1 = (unsigned int)f2bf(sv.z) | ((unsigned int)f2bf(sv.w) << 16);
    p10 = (unsigned int)f2bf(t1x) | ((unsigned int)f2bf(t1y) << 16);
    p11 = (unsigned int)f2bf(t1z) | ((unsigned int)f2bf(t1w) << 16);
    p20 = (unsigned int)f2bf(t2x) | ((unsigned int)f2bf(t2y) << 16);
    p21 = (unsigned int)f2bf(t2z) | ((unsigned int)f2bf(t2w) << 16);
  }
  unsigned int* crow = (unsigned int*)(comb + (size_t)b * KPAD);
  crow[2 * t]       = ps0;  crow[2 * t + 1]       = ps1;
  crow[160 + 2 * t] = p10;  crow[160 + 2 * t + 1] = p11;
  crow[320 + 2 * t] = p20;  crow[320 + 2 * t + 1] = p21;
}

__global__ void seg_bounds_only(const int* __restrict__ seg, int* __restrict__ start) {
  int i = blockIdx.x * 256 + threadIdx.x;
  if (i >= NEDGE) return;
  int s = seg[i];
  int prev = (i == 0) ? -1 : seg[i - 1];
  if (s != prev) for (int b = prev + 1; b <= s; ++b) start[b] = i;
  if (i == NEDGE - 1) for (int b = s + 1; b <= BQ; ++b) start[b] = NEDGE;
}
__global__ void prep_w_only(const float* __restrict__ W1, unsigned short* __restrict__ Wt) {
  int i = blockIdx.x * 256 + threadIdx.x;
  if (i >= NPAD * KPAD) return;
  int n = i / KPAD, k = i % KPAD;
  int sec = k / 320, kk = k % 320;
  unsigned short v = 0;
  if (n < 300 && kk < 300) v = f2bf(W1[n * 900 + sec * 300 + kk]);
  Wt[i] = v;
}

// ---------------------------------------------------------------------------
extern "C" void kernel_launch(void* const* d_in, const int* in_sizes, int n_in,
                              void* d_out, int out_size, void* d_ws, size_t ws_size,
                              hipStream_t stream) {
  const int* nodes     = (const int*)d_in[0];
  const int* seg       = (const int*)d_in[1];
  const int* neighbors = (const int*)d_in[2];
  const float* emb     = (const float*)d_in[3];
  const float* W1      = (const float*)d_in[4];
  const float* b1      = (const float*)d_in[5];
  float* out           = (float*)d_out;

  // Workspace layout:
  //   [0, 131584)       start[BQ+1] int
  //   [131584, 746496)  Wt [320][960] bf16 (614400 B + pad)
  //   [746496, 63661056)            comb [32768][960] bf16
  //   [63661056, 82258816)          embB [29059][320] bf16
  char* ws = (char*)d_ws;
  int* start           = (int*)ws;
  unsigned short* Wt   = (unsigned short*)(ws + 131584);
  unsigned short* comb = (unsigned short*)(ws + 746496);
  unsigned short* embB = (unsigned short*)(ws + 63661056);
  const size_t WS_NEEDED = 82258816;

  // one-time opt-in for 72 KB dynamic LDS on the big-tile GEMM
  static int big_lds_ok = -1;
  if (big_lds_ok < 0) {
    big_lds_ok = (hipFuncSetAttribute(
                      reinterpret_cast<const void*>(gemm),
                      hipFuncAttributeMaxDynamicSharedMemorySize,
                      73728) == hipSuccess) ? 1 : 0;
  }

  if (ws_size >= WS_NEEDED) {
    prep_all<<<SEG_BLOCKS + PW_BLOCKS + CE_BLOCKS, 256, 0, stream>>>(
        seg, start, W1, Wt, emb, embB);
    pool<<<BQ / 2, 128, 0, stream>>>(nodes, neighbors, start, embB, comb);
  } else {
    seg_bounds_only<<<SEG_BLOCKS, 256, 0, stream>>>(seg, start);
    prep_w_only<<<PW_BLOCKS, 256, 0, stream>>>(W1, Wt);
    pool_f32<<<BQ, 128, 0, stream>>>(nodes, neighbors, start, emb, comb);
  }
  if (big_lds_ok) {
    gemm<<<512, 256, 73728, stream>>>(comb, Wt, b1, out);
  } else {
    gemm_fb<<<1024, 256, 0, stream>>>(comb, Wt, b1, out);
  }
}